// Round 3
// baseline (649.959 us; speedup 1.0000x reference)
//
#include <hip/hip_runtime.h>

typedef unsigned short u16;
typedef short short8 __attribute__((ext_vector_type(8)));   // 8 bf16 as i16 (guide-verified MFMA operand type)
typedef float f32x4 __attribute__((ext_vector_type(4)));
typedef unsigned short u16x4 __attribute__((ext_vector_type(4)));

#define NEG_MASK -4294967295.0f   // -2^32+1 in f32

__device__ __forceinline__ u16 f2bf(float f) {
    unsigned int x = __float_as_uint(f);
    unsigned int r = (x + 0x7FFFu + ((x >> 16) & 1u)) >> 16;   // RNE
    return (u16)r;
}

// B=4096, T=200 (13 tiles of 16), D=64, H1=80, H2=40(pad 48, K2 pad 96), C=64
// All float tensors are FLOAT32 (reference dtype). MFMA operands staged as bf16.
// Static LDS total ~63.8 KB (< 64 KiB per-block cap; 2 blocks/CU in 160 KB pool).
__global__ __launch_bounds__(256) void din_kernel(
    const float* __restrict__ qp, const float* __restrict__ kp,
    const int* __restrict__ maskp, const int* __restrict__ catep,
    const float* __restrict__ W1p, const float* __restrict__ b1p,
    const float* __restrict__ a1p, const float* __restrict__ W2p,
    const float* __restrict__ b2p, const float* __restrict__ a2p,
    const float* __restrict__ wfp, const float* __restrict__ bfp,
    float* __restrict__ outp)
{
    __shared__ __align__(16) u16 Kt[200*64];                 // k[b] as bf16, stride 64: 25600 B
    // Mt (B-op GEMM1, [h][d], stride 72) | W2t (B-op GEMM2, [g][h], stride 104, zero-padded)
    // Reused after the GEMM phase as cate_acc[64][64] f32 (16384 B <= 21504 B)
    __shared__ __align__(16) u16 MtW2t[80*72 + 48*104];      // 21504 B
    __shared__ __align__(16) u16 H1p[4*16*104];              // per-wave A-op buf: 13312 B
    __shared__ float logits_s[200];
    __shared__ float q_s[64], qW_s[80], a1_s[80];
    __shared__ float a2_s[48], b2_s[48], wf_s[48];
    __shared__ float s_c[64], red_s[8], bf_s;
    __shared__ int cate_s[200];

    u16* Mt  = MtW2t;
    u16* W2t = MtW2t + 80*72;
    float* cate_acc = (float*)MtW2t;

    const int tid  = threadIdx.x;
    const int b    = blockIdx.x;
    const int wid  = tid >> 6;
    const int lane = tid & 63;
    const int i16  = lane & 15;
    const int q4   = lane >> 4;
    const float* kb = kp + (size_t)b * 12800;   // k[b] : [200][64] f32

    // ---------- Phase 0a: zeros + scalar staging ----------
    {
        unsigned int* w2z = (unsigned int*)W2t;
        for (int i = tid; i < (48*104)/2; i += 256) w2z[i] = 0u;  // W2t pad rows/cols
    }
    for (int i = tid; i < 4*16*12; i += 256) {   // H1p K-pad cols 80..103 (k=80..95 must be 0)
        int buf = i / 192, rem = i % 192, row = rem / 12, j = rem % 12;
        *(unsigned int*)&H1p[buf*(16*104) + row*104 + 80 + j*2] = 0u;
    }
    if (tid < 64) { s_c[tid] = 0.f; q_s[tid] = qp[(size_t)b*64 + tid]; }
    if (tid < 48) {
        wf_s[tid] = (tid < 40) ? wfp[tid] : 0.f;
        a2_s[tid] = (tid < 40) ? a2p[tid] : 0.f;
        b2_s[tid] = (tid < 40) ? b2p[tid] : 0.f;
    }
    if (tid < 80) a1_s[tid] = a1p[tid];
    if (tid == 0) bf_s = bfp[0];
    if (tid < 200) cate_s[tid] = catep[(size_t)b*200 + tid];
    // k[b] f32 -> bf16 LDS tile (coalesced float4)
    for (int c = tid; c < 3200; c += 256) {      // 200 rows * 16 float4
        float4 v = *(const float4*)(kb + c*4);
        u16x4 o = { f2bf(v.x), f2bf(v.y), f2bf(v.z), f2bf(v.w) };
        *(u16x4*)&Kt[c*4] = o;
    }
    __syncthreads();

    // ---------- Phase 0b: folded first-layer operands ----------
    // info@W1 = q@(W1a+W1c) + k@(W1b-W1c+diag(q)W1d);  Mt[h][d] = (W1b-W1c+q_d W1d)[d][h]
    for (int g = tid; g < 1280; g += 256) {
        int h = g % 80, d4 = (g / 80) * 4;
        u16x4 mv;
        #pragma unroll
        for (int i = 0; i < 4; ++i) {
            int d = d4 + i;
            float m = W1p[(64+d)*80 + h] - W1p[(128+d)*80 + h]
                    + q_s[d] * W1p[(192+d)*80 + h];
            mv[i] = f2bf(m);
        }
        *(u16x4*)&Mt[h*72 + d4] = mv;
    }
    if (tid < 80) {   // qW[h] = b1 + q@(W1a + W1c)   (exact f32)
        float acc = b1p[tid];
        #pragma unroll 4
        for (int d = 0; d < 64; ++d)
            acc += q_s[d] * (W1p[d*80 + tid] + W1p[(128+d)*80 + tid]);
        qW_s[tid] = acc;
    }
    for (int e = tid; e < 3200; e += 256) {   // W2t[g][h] = bf16(W2[h][g])
        int n = e % 40, kk = e / 40;
        W2t[n*104 + kk] = f2bf(W2p[e]);
    }
    __syncthreads();

    // ---------- Phase 1: MLP via MFMA, one 16-row t-tile per wave ----------
    u16* hb = &H1p[wid * (16*104)];
    for (int mt = wid; mt < 13; mt += 4) {
        int arow = mt*16 + i16; if (arow > 199) arow = 199;  // clamp tail (rows discarded)
        short8 ka0 = *(const short8*)&Kt[arow*64 + q4*8];        // A[m][k] k=0..31
        short8 ka1 = *(const short8*)&Kt[arow*64 + 32 + q4*8];   // k=32..63
        #pragma unroll
        for (int nt = 0; nt < 5; ++nt) {
            int n0 = nt*16;
            float qwv = qW_s[n0 + i16];
            f32x4 acc = { qwv, qwv, qwv, qwv };
            short8 b0 = *(const short8*)&Mt[(n0+i16)*72 + q4*8];
            short8 b1 = *(const short8*)&Mt[(n0+i16)*72 + 32 + q4*8];
            acc = __builtin_amdgcn_mfma_f32_16x16x32_bf16(ka0, b0, acc, 0, 0, 0);
            acc = __builtin_amdgcn_mfma_f32_16x16x32_bf16(ka1, b1, acc, 0, 0, 0);
            float al = a1_s[n0 + i16];
            #pragma unroll
            for (int r = 0; r < 4; ++r) {    // PReLU + C-layout (row=q4*4+r, col=i16) -> A-layout LDS
                float x = acc[r];
                float y = (x > 0.f) ? x : al * x;
                hb[(q4*4 + r)*104 + n0 + i16] = f2bf(y);
            }
        }
        short8 A0 = *(const short8*)&hb[i16*104 + q4*8];
        short8 A1 = *(const short8*)&hb[i16*104 + 32 + q4*8];
        short8 A2 = *(const short8*)&hb[i16*104 + 64 + q4*8];
        float part0 = 0.f, part1 = 0.f, part2 = 0.f, part3 = 0.f;
        #pragma unroll
        for (int nt = 0; nt < 3; ++nt) {
            int n0 = nt*16;
            float b2v = b2_s[n0 + i16];
            f32x4 acc = { b2v, b2v, b2v, b2v };
            short8 w0 = *(const short8*)&W2t[(n0+i16)*104 + q4*8];
            short8 w1 = *(const short8*)&W2t[(n0+i16)*104 + 32 + q4*8];
            short8 w2 = *(const short8*)&W2t[(n0+i16)*104 + 64 + q4*8];
            acc = __builtin_amdgcn_mfma_f32_16x16x32_bf16(A0, w0, acc, 0, 0, 0);
            acc = __builtin_amdgcn_mfma_f32_16x16x32_bf16(A1, w1, acc, 0, 0, 0);
            acc = __builtin_amdgcn_mfma_f32_16x16x32_bf16(A2, w2, acc, 0, 0, 0);
            float al2 = a2_s[n0 + i16];
            float wfv = wf_s[n0 + i16];   // zero-padded cols 40..47 contribute 0
            float x, y;
            x = acc[0]; y = (x > 0.f) ? x : al2*x; part0 += y*wfv;
            x = acc[1]; y = (x > 0.f) ? x : al2*x; part1 += y*wfv;
            x = acc[2]; y = (x > 0.f) ? x : al2*x; part2 += y*wfv;
            x = acc[3]; y = (x > 0.f) ? x : al2*x; part3 += y*wfv;
        }
        #pragma unroll
        for (int off = 1; off < 16; off <<= 1) {   // reduce across the 16 col-lanes
            part0 += __shfl_xor(part0, off, 64);
            part1 += __shfl_xor(part1, off, 64);
            part2 += __shfl_xor(part2, off, 64);
            part3 += __shfl_xor(part3, off, 64);
        }
        if (i16 == 0) {
            float p0[4] = { part0, part1, part2, part3 };
            #pragma unroll
            for (int r = 0; r < 4; ++r) {
                int t = mt*16 + q4*4 + r;
                if (t < 200) {
                    int mv = maskp[(size_t)b*200 + t];
                    float v = (mv == 0) ? NEG_MASK : (bf_s + p0[r]);
                    logits_s[t] = v * 0.125f;   // /sqrt(64)
                }
            }
        }
    }
    __syncthreads();

    // ---------- Phase 2: softmax + per-category weight sums ----------
    for (int i = tid; i < 4096; i += 256) cate_acc[i] = 0.f;   // Mt/W2t dead now
    float x = (tid < 200) ? logits_s[tid] : -3.0e38f;
    float m = x;
    #pragma unroll
    for (int off = 32; off >= 1; off >>= 1) m = fmaxf(m, __shfl_xor(m, off, 64));
    if (lane == 0) red_s[wid] = m;
    __syncthreads();
    float mx = fmaxf(fmaxf(red_s[0], red_s[1]), fmaxf(red_s[2], red_s[3]));
    float e = (tid < 200) ? __expf(x - mx) : 0.f;   // masked rows underflow to exact 0
    float s = e;
    #pragma unroll
    for (int off = 32; off >= 1; off >>= 1) s += __shfl_xor(s, off, 64);
    if (lane == 0) red_s[4 + wid] = s;
    __syncthreads();
    float tot = red_s[4] + red_s[5] + red_s[6] + red_s[7];
    float wv = e / tot;
    if (tid < 200) {
        logits_s[tid] = wv;   // reuse as w[t]
        if (wv > 0.f) atomicAdd(&s_c[cate_s[tid]], wv);
    }
    __syncthreads();

    // ---------- Phase 3: pooling (k rows re-read as exact f32, L1/L2-hot) ----------
    for (int t = wid; t < 200; t += 4) {   // lanes = d
        float wt = logits_s[t];
        if (wt > 0.f) {
            int c = cate_s[t];
            float kd = kb[t*64 + lane];
            atomicAdd(&cate_acc[c*64 + lane], wt * kd);
        }
    }
    __syncthreads();
    if (tid < 64) {   // user_interest = sum over categories of raw weighted sums
        float ui = 0.f;
        #pragma unroll 8
        for (int c = 0; c < 64; ++c) ui += cate_acc[c*64 + tid];
        outp[(size_t)b*64 + tid] = ui;
    }
    for (int i = tid; i < 4096; i += 256) {
        int c = i >> 6;
        float v = cate_acc[i] / (s_c[c] + 1e-10f);
        outp[(size_t)(4096*64) + (size_t)b*4096 + i] = v;
    }
}

extern "C" void kernel_launch(void* const* d_in, const int* in_sizes, int n_in,
                              void* d_out, int out_size, void* d_ws, size_t ws_size,
                              hipStream_t stream) {
    din_kernel<<<4096, 256, 0, stream>>>(
        (const float*)d_in[0],   // q
        (const float*)d_in[1],   // k
        (const int*)d_in[2],     // mask
        (const int*)d_in[3],     // hist_cate
        (const float*)d_in[5],   // W1 (d_in[4] = cate_count scalar)
        (const float*)d_in[6],   // b1
        (const float*)d_in[7],   // a1
        (const float*)d_in[8],   // W2
        (const float*)d_in[9],   // b2
        (const float*)d_in[10],  // a2
        (const float*)d_in[11],  // Wf
        (const float*)d_in[12],  // bf
        (float*)d_out);
}

// Round 4
// 581.155 us; speedup vs baseline: 1.1184x; 1.1184x over previous
//
#include <hip/hip_runtime.h>

typedef unsigned short u16;
typedef short short8 __attribute__((ext_vector_type(8)));   // 8 bf16 as i16 (MFMA operand)
typedef float f32x4 __attribute__((ext_vector_type(4)));

#define NEG_MASK -4294967295.0f   // -2^32+1 in f32

__device__ __forceinline__ u16 f2bf(float f) {
    unsigned int x = __float_as_uint(f);
    unsigned int r = (x + 0x7FFFu + ((x >> 16) & 1u)) >> 16;   // RNE
    return (u16)r;
}
__device__ __forceinline__ short8 cvt8(float4 a, float4 b) {
    union { short8 v; u16 u[8]; } r;
    r.u[0] = f2bf(a.x); r.u[1] = f2bf(a.y); r.u[2] = f2bf(a.z); r.u[3] = f2bf(a.w);
    r.u[4] = f2bf(b.x); r.u[5] = f2bf(b.y); r.u[6] = f2bf(b.z); r.u[7] = f2bf(b.w);
    return r.v;
}

// B=4096, T=200 (13 tiles of 16), D=64, H1=80, H2=40(pad 48, K2 pad 96), C=64
// LDS ~38.2 KB -> 4 blocks/CU (was 64 KB -> 2 blocks/CU: the round-3 latency wall).
// A-fragments (k) are read per-tile from global f32 (coalesced dwordx4) and
// converted to bf16 in-register -- no Kt LDS tile.
__global__ __launch_bounds__(256) void din_kernel(
    const float* __restrict__ qp, const float* __restrict__ kp,
    const int* __restrict__ maskp, const int* __restrict__ catep,
    const float* __restrict__ W1p, const float* __restrict__ b1p,
    const float* __restrict__ a1p, const float* __restrict__ W2p,
    const float* __restrict__ b2p, const float* __restrict__ a2p,
    const float* __restrict__ wfp, const float* __restrict__ bfp,
    float* __restrict__ outp)
{
    // Mt (B-op GEMM1, [h][d], stride 72) | W2t (B-op GEMM2, [g][h], stride 104, zero-padded)
    // Reused after the GEMM phase as cate_acc[64][64] f32 (16384 B <= 21504 B)
    __shared__ __align__(16) u16 MtW2t[80*72 + 48*104];      // 21504 B
    __shared__ __align__(16) u16 H1p[4*16*104];              // per-wave A-op buf: 13312 B
    __shared__ float logits_s[200];                          // phase0: qW partials alias
    __shared__ float q_s[64], qW_s[80], a1_s[80];
    __shared__ float a2_s[48], b2_s[48], wf_s[48];
    __shared__ float s_c[64], red_s[8], bf_s;
    __shared__ int cate_s[200];

    u16* Mt  = MtW2t;
    u16* W2t = MtW2t + 80*72;
    float* cate_acc = (float*)MtW2t;
    float* qW2 = logits_s;   // alias: dead before logits are first written (phase 1)

    const int tid  = threadIdx.x;
    const int b    = blockIdx.x;
    const int wid  = tid >> 6;
    const int lane = tid & 63;
    const int i16  = lane & 15;
    const int q4   = lane >> 4;
    const float* kb = kp + (size_t)b * 12800;   // k[b] : [200][64] f32

    // ---------- Phase 0a: zeros + scalar staging ----------
    {
        unsigned int* w2z = (unsigned int*)W2t;
        for (int i = tid; i < (48*104)/2; i += 256) w2z[i] = 0u;  // W2t pad rows/cols
    }
    for (int i = tid; i < 4*16*12; i += 256) {   // H1p K-pad cols 80..103 (k=80..95 must be 0)
        int buf = i / 192, rem = i % 192, row = rem / 12, j = rem % 12;
        *(unsigned int*)&H1p[buf*(16*104) + row*104 + 80 + j*2] = 0u;
    }
    if (tid < 64) { s_c[tid] = 0.f; q_s[tid] = qp[(size_t)b*64 + tid]; }
    if (tid < 48) {
        wf_s[tid] = (tid < 40) ? wfp[tid] : 0.f;
        a2_s[tid] = (tid < 40) ? a2p[tid] : 0.f;
        b2_s[tid] = (tid < 40) ? b2p[tid] : 0.f;
    }
    if (tid < 80) a1_s[tid] = a1p[tid];
    if (tid == 0) bf_s = bfp[0];
    if (tid < 200) cate_s[tid] = catep[(size_t)b*200 + tid];
    __syncthreads();

    // ---------- Phase 0b: folded first-layer operands (all-coalesced W1 reads) ----------
    // info@W1 = q@(W1a+W1c) + k@(W1b-W1c+diag(q)W1d);  Mt[h][d] = (W1b-W1c+q_d W1d)[d][h]
    for (int j = tid; j < 5120; j += 256) {      // j = d*80 + h : 3 coalesced streams
        int d = j / 80, h = j - d*80;
        float m = W1p[5120 + j] - W1p[10240 + j] + q_s[d] * W1p[15360 + j];
        Mt[h*72 + d] = f2bf(m);                  // u16 scatter into LDS (cheap vs L2 scatter)
    }
    if (tid < 160) {                             // qW partials: 2 x 80 threads x 32 iters
        int p = tid >> 7 ? 1 : (tid / 80), h = tid - (tid / 80) * 80;
        p = tid / 80;
        float acc = 0.f;
        int d0 = p * 32;
        #pragma unroll 4
        for (int d = d0; d < d0 + 32; ++d)
            acc += q_s[d] * (W1p[d*80 + h] + W1p[(128+d)*80 + h]);
        qW2[tid] = acc;
    }
    for (int e = tid; e < 3200; e += 256) {      // W2t[g][h] = bf16(W2[h][g])
        int n = e % 40, kk = e / 40;
        W2t[n*104 + kk] = f2bf(W2p[e]);
    }
    __syncthreads();
    if (tid < 80) qW_s[tid] = b1p[tid] + qW2[tid] + qW2[80 + tid];
    __syncthreads();

    // ---------- Phase 1: MLP via MFMA, one 16-row t-tile per wave ----------
    u16* hb = &H1p[wid * (16*104)];
    for (int mt = wid; mt < 13; mt += 4) {
        int arow = mt*16 + i16; if (arow > 199) arow = 199;  // clamp tail (rows discarded)
        const float4* kr = (const float4*)(kb + arow*64);
        float4 f0 = kr[2*q4], f1 = kr[2*q4 + 1];             // k cols q4*8..q4*8+7
        float4 f2 = kr[8 + 2*q4], f3 = kr[9 + 2*q4];         // k cols 32+q4*8..
        short8 ka0 = cvt8(f0, f1);
        short8 ka1 = cvt8(f2, f3);
        #pragma unroll
        for (int nt = 0; nt < 5; ++nt) {
            int n0 = nt*16;
            float qwv = qW_s[n0 + i16];
            f32x4 acc = { qwv, qwv, qwv, qwv };
            short8 b0 = *(const short8*)&Mt[(n0+i16)*72 + q4*8];
            short8 b1 = *(const short8*)&Mt[(n0+i16)*72 + 32 + q4*8];
            acc = __builtin_amdgcn_mfma_f32_16x16x32_bf16(ka0, b0, acc, 0, 0, 0);
            acc = __builtin_amdgcn_mfma_f32_16x16x32_bf16(ka1, b1, acc, 0, 0, 0);
            float al = a1_s[n0 + i16];
            #pragma unroll
            for (int r = 0; r < 4; ++r) {    // PReLU + C-layout (row=q4*4+r, col=i16) -> A-layout LDS
                float x = acc[r];
                float y = (x > 0.f) ? x : al * x;
                hb[(q4*4 + r)*104 + n0 + i16] = f2bf(y);
            }
        }
        short8 A0 = *(const short8*)&hb[i16*104 + q4*8];
        short8 A1 = *(const short8*)&hb[i16*104 + 32 + q4*8];
        short8 A2 = *(const short8*)&hb[i16*104 + 64 + q4*8];
        float part0 = 0.f, part1 = 0.f, part2 = 0.f, part3 = 0.f;
        #pragma unroll
        for (int nt = 0; nt < 3; ++nt) {
            int n0 = nt*16;
            float b2v = b2_s[n0 + i16];
            f32x4 acc = { b2v, b2v, b2v, b2v };
            short8 w0 = *(const short8*)&W2t[(n0+i16)*104 + q4*8];
            short8 w1 = *(const short8*)&W2t[(n0+i16)*104 + 32 + q4*8];
            short8 w2 = *(const short8*)&W2t[(n0+i16)*104 + 64 + q4*8];
            acc = __builtin_amdgcn_mfma_f32_16x16x32_bf16(A0, w0, acc, 0, 0, 0);
            acc = __builtin_amdgcn_mfma_f32_16x16x32_bf16(A1, w1, acc, 0, 0, 0);
            acc = __builtin_amdgcn_mfma_f32_16x16x32_bf16(A2, w2, acc, 0, 0, 0);
            float al2 = a2_s[n0 + i16];
            float wfv = wf_s[n0 + i16];   // zero-padded cols 40..47 contribute 0
            float x, y;
            x = acc[0]; y = (x > 0.f) ? x : al2*x; part0 += y*wfv;
            x = acc[1]; y = (x > 0.f) ? x : al2*x; part1 += y*wfv;
            x = acc[2]; y = (x > 0.f) ? x : al2*x; part2 += y*wfv;
            x = acc[3]; y = (x > 0.f) ? x : al2*x; part3 += y*wfv;
        }
        #pragma unroll
        for (int off = 1; off < 16; off <<= 1) {   // reduce across the 16 col-lanes
            part0 += __shfl_xor(part0, off, 64);
            part1 += __shfl_xor(part1, off, 64);
            part2 += __shfl_xor(part2, off, 64);
            part3 += __shfl_xor(part3, off, 64);
        }
        if (i16 == 0) {
            float p0[4] = { part0, part1, part2, part3 };
            #pragma unroll
            for (int r = 0; r < 4; ++r) {
                int t = mt*16 + q4*4 + r;
                if (t < 200) {
                    int mv = maskp[(size_t)b*200 + t];
                    float v = (mv == 0) ? NEG_MASK : (bf_s + p0[r]);
                    logits_s[t] = v * 0.125f;   // /sqrt(64)
                }
            }
        }
    }
    __syncthreads();

    // ---------- Phase 2: softmax + per-category weight sums ----------
    for (int i = tid; i < 4096; i += 256) cate_acc[i] = 0.f;   // Mt/W2t dead now
    float x = (tid < 200) ? logits_s[tid] : -3.0e38f;
    float m = x;
    #pragma unroll
    for (int off = 32; off >= 1; off >>= 1) m = fmaxf(m, __shfl_xor(m, off, 64));
    if (lane == 0) red_s[wid] = m;
    __syncthreads();
    float mx = fmaxf(fmaxf(red_s[0], red_s[1]), fmaxf(red_s[2], red_s[3]));
    float e = (tid < 200) ? __expf(x - mx) : 0.f;   // masked rows underflow to exact 0
    float s = e;
    #pragma unroll
    for (int off = 32; off >= 1; off >>= 1) s += __shfl_xor(s, off, 64);
    if (lane == 0) red_s[4 + wid] = s;
    __syncthreads();
    float tot = red_s[4] + red_s[5] + red_s[6] + red_s[7];
    float wv = e / tot;
    if (tid < 200) {
        logits_s[tid] = wv;   // reuse as w[t]
        if (wv > 0.f) atomicAdd(&s_c[cate_s[tid]], wv);
    }
    __syncthreads();

    // ---------- Phase 3: pooling (k rows re-read as exact f32, L2/L3-hot) ----------
    #pragma unroll 2
    for (int t = wid; t < 200; t += 4) {   // lanes = d
        float wt = logits_s[t];
        if (wt > 0.f) {
            int c = cate_s[t];
            float kd = kb[t*64 + lane];
            atomicAdd(&cate_acc[c*64 + lane], wt * kd);
        }
    }
    __syncthreads();
    if (tid < 64) {   // user_interest = sum over categories of raw weighted sums
        float ui = 0.f;
        #pragma unroll 8
        for (int c = 0; c < 64; ++c) ui += cate_acc[c*64 + tid];
        outp[(size_t)b*64 + tid] = ui;
    }
    for (int i = tid; i < 4096; i += 256) {
        int c = i >> 6;
        float v = cate_acc[i] / (s_c[c] + 1e-10f);
        outp[(size_t)(4096*64) + (size_t)b*4096 + i] = v;
    }
}

extern "C" void kernel_launch(void* const* d_in, const int* in_sizes, int n_in,
                              void* d_out, int out_size, void* d_ws, size_t ws_size,
                              hipStream_t stream) {
    din_kernel<<<4096, 256, 0, stream>>>(
        (const float*)d_in[0],   // q
        (const float*)d_in[1],   // k
        (const int*)d_in[2],     // mask
        (const int*)d_in[3],     // hist_cate
        (const float*)d_in[5],   // W1 (d_in[4] = cate_count scalar)
        (const float*)d_in[6],   // b1
        (const float*)d_in[7],   // a1
        (const float*)d_in[8],   // W2
        (const float*)d_in[9],   // b2
        (const float*)d_in[10],  // a2
        (const float*)d_in[11],  // Wf
        (const float*)d_in[12],  // bf
        (float*)d_out);
}